// Round 7
// baseline (1983.808 us; speedup 1.0000x reference)
//
#include <hip/hip_runtime.h>

typedef short bf16x8 __attribute__((ext_vector_type(8)));
typedef float f32x4  __attribute__((ext_vector_type(4)));

#define Bb 128
#define Nn 512
#define Ff 16
#define Hh 128
#define HIST 24
#define FW 24
#define Ee 8192
#define BN (Bb*Nn)      // 65536
#define NE (Bb*Ee)      // 1048576
#define THIST (HIST+FW) // 48
#define NSLOT 20        // K=160 -> 20 slots of 8 bf16
#define WPN (4*8*NSLOT*16*8)   // 81920 bf16 elements
#define LDS_BYTES 141312       // 128K h + 4K x2 + 4K xn + 2K xnpart

__device__ __forceinline__ unsigned short f2bfu(float x){
  union { float f; unsigned u; } v; v.f = x;
  unsigned r = v.u + 0x7FFFu + ((v.u >> 16) & 1u);
  return (unsigned short)(r >> 16);
}
__device__ __forceinline__ float sigm(float x){ return 1.f/(1.f + __expf(-x)); }
__device__ __forceinline__ float tanh_f(float x){ return 1.f - 2.f/(__expf(2.f*x) + 1.f); }

// ---------------- one-shot local CSR (graph identical across batches) ----------------
__global__ __launch_bounds__(512) void k_csr(const int* __restrict__ eidx, int* __restrict__ rowptrL,
                                             int* __restrict__ srcsL, float* __restrict__ invdegL){
  __shared__ int cnt[512];
  __shared__ int scan[512];
  int tid = threadIdx.x;
  cnt[tid] = 0;
  __syncthreads();
  for (int e = tid; e < Ee; e += 512) atomicAdd(&cnt[eidx[NE + e]], 1);
  __syncthreads();
  int c = cnt[tid];
  scan[tid] = c;
  __syncthreads();
  for (int off = 1; off < 512; off <<= 1){
    int v = (tid >= off) ? scan[tid-off] : 0;
    __syncthreads();
    scan[tid] += v;
    __syncthreads();
  }
  int excl = scan[tid] - c;
  rowptrL[tid] = excl;
  if (tid == 0) rowptrL[512] = Ee;
  invdegL[tid] = 1.0f / fmaxf((float)c, 1.0f);
  __syncthreads();
  scan[tid] = excl;
  cnt[tid] = 0;
  __syncthreads();
  for (int e = tid; e < Ee; e += 512){
    int d = eidx[NE + e];
    int pos = scan[d] + atomicAdd(&cnt[d], 1);
    srcsL[pos] = eidx[e];
  }
}

// Pack Wbig[128 cols x 4 gates][K=160] into B-frag order.
// flat = (((g*8 + w)*20 + slot)*16 + c)*8 + j ; col = w*16 + c ; k = slot*8 + j
// K: [0,18)=x2=[xn,f0..f15,gcn]; [18,32)=0; [32,160)=h
__global__ __launch_bounds__(256) void k_wpack(const float* __restrict__ W_ih, const float* __restrict__ W_hh,
                                               unsigned short* __restrict__ Wpack){
  int idx = blockIdx.x*256 + threadIdx.x;
  if (idx >= WPN) return;
  int j = idx & 7;
  int r = idx >> 3;
  int c = r & 15; r >>= 4;
  int slot = r % NSLOT; r /= NSLOT;
  int w = r & 7; int g = r >> 3;
  int k = slot*8 + j;
  int col = w*16 + c;               // 0..127
  float v = 0.f;
  if (g == 0 || g == 1){            // r, z : fused x2 + h
    int row = (g == 0) ? col : 128 + col;
    if (k < 32){ if (k < 18) v = W_ih[row*18 + k]; }
    else v = W_hh[(size_t)row*128 + (k-32)];
  } else if (g == 2){               // i_n : x2 only
    if (k < 18) v = W_ih[(256+col)*18 + k];
  } else {                          // h_n : h only
    if (k >= 32) v = W_hh[(size_t)(256+col)*128 + (k-32)];
  }
  Wpack[idx] = f2bfu(v);
}

// sfeat = feat·W_nb[1:17]; pre(rootf) = feat·W_root[1:17]; xfb = bf16(feat)
__global__ __launch_bounds__(256) void k_sfeat(const float* __restrict__ feature, const float* __restrict__ W_nb,
                                               const float* __restrict__ W_root,
                                               float* __restrict__ sfeat, float* __restrict__ rootf,
                                               unsigned short* __restrict__ xfb){
  int idx = blockIdx.x*256 + threadIdx.x;
  if (idx >= FW*BN) return;
  int t = idx >> 16, g = idx & 0xFFFF;
  int b = g>>9, n = g&511;
  const float* f = feature + (((size_t)b*THIST + HIST + t)*Nn + n)*Ff;
  unsigned short xv[16];
  float s = 0.f, r = 0.f;
  #pragma unroll
  for (int k = 0; k < Ff; k++){
    float v = f[k];
    s = fmaf(v, W_nb[1+k], s); r = fmaf(v, W_root[1+k], r);
    xv[k] = f2bfu(v);
  }
  sfeat[idx] = s; rootf[idx] = r;
  *(bf16x8*)&xfb[(size_t)idx*16]     = *(bf16x8*)&xv[0];
  *(bf16x8*)&xfb[(size_t)idx*16 + 8] = *(bf16x8*)&xv[8];
}

// pre[t][g] = invdegL[n]*sum sfeat[t][b][src] + pre[t][g] + b_nb
__global__ __launch_bounds__(256) void k_aggT(const int* __restrict__ rowptrL, const int* __restrict__ srcsL,
                                              const float* __restrict__ sfeat, const float* __restrict__ invdegL,
                                              const float* __restrict__ b_nb, float* __restrict__ pre){
  int idx = blockIdx.x*256 + threadIdx.x;
  if (idx >= FW*BN) return;
  int g = idx & 0xFFFF, t = idx >> 16;
  int n = g & 511, b = g >> 9;
  int e0 = rowptrL[n], e1 = rowptrL[n+1];
  const float* sf = sfeat + (size_t)t*BN + (size_t)b*Nn;
  float s = 0.f;
  for (int e = e0; e < e1; e++) s += sf[srcsL[e]];
  pre[idx] = invdegL[n]*s + pre[idx] + b_nb[0];
}

// ---------------- persistent fused recurrence: one block = one batch ----------------
// 512 thr = 8 waves. h state: bf16 in LDS (GEMM A operand, XOR-swizzled) + fp32 master in
// global (L2-local, exact z*h_old). xn double-buffered in LDS. 8 tiles of 64 nodes/step.
// Wave w owns gate-cols j = w*16 + (lane&15) of all 4 gates -> epilogue register-local.
__global__ __launch_bounds__(512, 2) void k_fused(
    const float* __restrict__ pm, const float* __restrict__ pre,
    const float* __restrict__ invdegL, const unsigned short* __restrict__ xfb,
    const int* __restrict__ rowptrL, const int* __restrict__ srcsL,
    const unsigned short* __restrict__ Wpack,
    const float* __restrict__ b_ih, const float* __restrict__ b_hh,
    const float* __restrict__ W_nb, const float* __restrict__ W_root,
    const float* __restrict__ W_out, const float* __restrict__ b_out,
    float* __restrict__ h_g, float* __restrict__ out)
{
  extern __shared__ char smem[];
  short* h_lds  = (short*)smem;                 // [512][128] bf16, chunk16B idx ^= row&15
  short* x2_lds = (short*)(smem + 131072);      // [4][64][8]
  float* xn_lds = (float*)(smem + 135168);      // [2][512]
  float* xnpart = (float*)(smem + 139264);      // [8][64]

  const int tid = threadIdx.x;
  const int b = blockIdx.x;
  const int l = tid & 63, w = tid >> 6;
  const int c = l & 15, lg = l >> 4;

  // init h=0, xn[0] = last pm25
  {
    bf16x8 z = {};
    for (int i = tid; i < 512*128/8; i += 512) ((bf16x8*)h_lds)[i] = z;
    xn_lds[tid] = pm[((size_t)b*HIST + (HIST-1))*Nn + tid];
  }
  __syncthreads();

  const int j = w*16 + c;
  const float bR = b_ih[j] + b_hh[j];
  const float bZ = b_ih[128+j] + b_hh[128+j];
  const float bI = b_ih[256+j];
  const float bH = b_hh[256+j];
  const float wo = W_out[j];
  const float wnb0 = W_nb[0], wrt0 = W_root[0], bo = b_out[0];

  for (int t = 0; t < FW; t++){
    const float* xn_cur = xn_lds + (t&1)*512;
    float* xn_nxt = xn_lds + ((t&1)^1)*512;
    const float* pre_t = pre + (size_t)t*BN + (size_t)b*Nn;
    const unsigned short* xfb_t = xfb + ((size_t)t*BN + (size_t)b*Nn)*16;

    for (int t8 = 0; t8 < 8; t8++){
      const int tb = t8*64;
      // --- phase A: SX gather (8 thr/node) + gcn + x2 stage ---
      {
        int m = tid >> 3, sub = tid & 7;
        int n = tb + m;
        int e0 = rowptrL[n], e1 = rowptrL[n+1];
        float sx = 0.f;
        for (int e = e0 + sub; e < e1; e += 8) sx += xn_cur[srcsL[e]];
        sx += __shfl_xor(sx, 1); sx += __shfl_xor(sx, 2); sx += __shfl_xor(sx, 4);
        if (sub == 0){
          float xv = xn_cur[n];
          float prea = pre_t[n] + invdegL[n]*wnb0*sx + wrt0*xv;
          float gcn = sigm(prea);
          const bf16x8* xf = (const bf16x8*)&xfb_t[(size_t)n*16];
          bf16x8 x0 = xf[0], x1 = xf[1];
          short v[32];
          v[0] = (short)f2bfu(xv);
          #pragma unroll
          for (int k = 0; k < 8; k++){ v[1+k] = x0[k]; v[9+k] = x1[k]; }
          v[17] = (short)f2bfu(gcn);
          #pragma unroll
          for (int k = 18; k < 32; k++) v[k] = 0;
          #pragma unroll
          for (int s = 0; s < 4; s++)
            *(bf16x8*)&x2_lds[(s*64 + m)*8] = *(bf16x8*)&v[s*8];
        }
      }
      __syncthreads();

      // --- phase B: GEMM [64 x 160] x [160 x 512] ---
      f32x4 acc[4][4] = {};   // [gate][m]
      #pragma unroll
      for (int kk = 0; kk < 5; kk++){
        bf16x8 a[4];
        if (kk == 0){
          #pragma unroll
          for (int m = 0; m < 4; m++)
            a[m] = *(const bf16x8*)&x2_lds[(lg*64 + m*16 + c)*8];
        } else {
          int sh = (kk-1)*4 + lg;
          #pragma unroll
          for (int m = 0; m < 4; m++){
            int row = tb + m*16 + c;
            a[m] = *(const bf16x8*)&h_lds[row*128 + ((sh ^ c)*8)];
          }
        }
        #pragma unroll
        for (int g = 0; g < 4; g++){
          const bf16x8 bv = *(const bf16x8*)&Wpack[(size_t)(((g*8 + w)*NSLOT + kk*4 + lg)*16 + c)*8];
          #pragma unroll
          for (int m = 0; m < 4; m++)
            acc[g][m] = __builtin_amdgcn_mfma_f32_16x16x32_bf16(a[m], bv, acc[g][m], 0, 0, 0);
        }
      }
      __syncthreads();

      // --- phase C: GRU epilogue (register-local), fp32 h master in global ---
      float psum[4][4];
      #pragma unroll
      for (int m = 0; m < 4; m++){
        #pragma unroll
        for (int q = 0; q < 4; q++){
          int row = tb + m*16 + lg*4 + q;
          size_t off = ((size_t)b*Nn + row)*Hh + j;
          float hold = (t == 0) ? 0.f : h_g[off];
          float rr = sigm(acc[0][m][q] + bR);
          float zz = sigm(acc[1][m][q] + bZ);
          float nn = tanh_f(acc[2][m][q] + bI + rr*(acc[3][m][q] + bH));
          float hv = (1.f - zz)*nn + zz*hold;
          h_g[off] = hv;
          int rl = lg*4 + q;
          h_lds[row*128 + (((j>>3) ^ rl)*8) + (j&7)] = (short)f2bfu(hv);
          psum[m][q] = hv * wo;
        }
      }
      #pragma unroll
      for (int mask = 1; mask < 16; mask <<= 1){
        #pragma unroll
        for (int m = 0; m < 4; m++)
          #pragma unroll
          for (int q = 0; q < 4; q++)
            psum[m][q] += __shfl_xor(psum[m][q], mask);
      }
      if (c == 0){
        #pragma unroll
        for (int m = 0; m < 4; m++)
          #pragma unroll
          for (int q = 0; q < 4; q++)
            xnpart[w*64 + m*16 + lg*4 + q] = psum[m][q];
      }
      __syncthreads();

      // --- phase D: xn finalize (runs concurrent with next tile's phase A) ---
      if (tid < 64){
        int row = tb + tid;
        float xv = bo;
        #pragma unroll
        for (int ww = 0; ww < 8; ww++) xv += xnpart[ww*64 + tid];
        xn_nxt[row] = xv;
        out[((size_t)b*FW + t)*Nn + row] = xv;
      }
    }
    __syncthreads();   // step boundary: xn_nxt complete before next step reads it
  }
}

extern "C" void kernel_launch(void* const* d_in, const int* in_sizes, int n_in,
                              void* d_out, int out_size, void* d_ws, size_t ws_size,
                              hipStream_t stream){
  const float* feature = (const float*)d_in[0];
  const float* pm25    = (const float*)d_in[1];
  const int*   eidx    = (const int*)d_in[2];
  const float* W_nb    = (const float*)d_in[3];
  const float* b_nb    = (const float*)d_in[4];
  const float* W_root  = (const float*)d_in[5];
  const float* W_ih    = (const float*)d_in[6];
  const float* W_hh    = (const float*)d_in[7];
  const float* b_ih    = (const float*)d_in[8];
  const float* b_hh    = (const float*)d_in[9];
  const float* W_out   = (const float*)d_in[10];
  const float* b_out   = (const float*)d_in[11];
  float* out = (float*)d_out;

  char* wsp = (char*)d_ws;
  float* invdegL = (float*)wsp; wsp += 512*4;
  int*   rowptrL = (int*)wsp;   wsp += 520*4;
  int*   srcsL   = (int*)wsp;   wsp += Ee*4;
  float* sfeat   = (float*)wsp; wsp += (size_t)FW*BN*4;
  float* pre     = (float*)wsp; wsp += (size_t)FW*BN*4;
  unsigned short* xfb = (unsigned short*)wsp; wsp += (size_t)FW*BN*16*2;
  unsigned short* Wpack = (unsigned short*)wsp; wsp += (size_t)WPN*2;
  float* h_g     = (float*)wsp; wsp += (size_t)BN*Hh*4;

  static int attr_set = 0;
  if (!attr_set){
    hipFuncSetAttribute((const void*)k_fused, hipFuncAttributeMaxDynamicSharedMemorySize, LDS_BYTES);
    attr_set = 1;
  }

  k_csr   <<<1, 512, 0, stream>>>(eidx, rowptrL, srcsL, invdegL);
  k_wpack <<<(WPN+255)/256, 256, 0, stream>>>(W_ih, W_hh, Wpack);
  k_sfeat <<<(FW*BN)/256, 256, 0, stream>>>(feature, W_nb, W_root, sfeat, pre, xfb);
  k_aggT  <<<(FW*BN)/256, 256, 0, stream>>>(rowptrL, srcsL, sfeat, invdegL, b_nb, pre);

  k_fused<<<Bb, 512, LDS_BYTES, stream>>>(pm25, pre, invdegL, xfb, rowptrL, srcsL, Wpack,
                                          b_ih, b_hh, W_nb, W_root, W_out, b_out, h_g, out);
}

// Round 8
// 1622.631 us; speedup vs baseline: 1.2226x; 1.2226x over previous
//
#include <hip/hip_runtime.h>
#include <hip/hip_fp16.h>

typedef short    bf16x8 __attribute__((ext_vector_type(8)));
typedef _Float16 f16x8  __attribute__((ext_vector_type(8)));
typedef float    f32x4  __attribute__((ext_vector_type(4)));

#define Bb 128
#define Nn 512
#define Ff 16
#define Hh 128
#define HIST 24
#define FW 24
#define Ee 8192
#define BN (Bb*Nn)      // 65536
#define NE (Bb*Ee)      // 1048576
#define THIST (HIST+FW) // 48
#define NSLOT 20        // K=160 -> 20 slots of 8 elems
#define WPN (4*8*NSLOT*16*8)   // 81920 elements
#define LDS_BYTES 141312       // 128K h(fp16) + 4K x2 + 4K xn + 2K xnpart

__device__ __forceinline__ unsigned short f2bfu(float x){
  union { float f; unsigned u; } v; v.f = x;
  unsigned r = v.u + 0x7FFFu + ((v.u >> 16) & 1u);
  return (unsigned short)(r >> 16);
}
__device__ __forceinline__ float sigm(float x){ return 1.f/(1.f + __expf(-x)); }
__device__ __forceinline__ float tanh_f(float x){ return 1.f - 2.f/(__expf(2.f*x) + 1.f); }

// ---------------- one-shot local CSR (graph identical across batches) ----------------
__global__ __launch_bounds__(512) void k_csr(const int* __restrict__ eidx, int* __restrict__ rowptrL,
                                             int* __restrict__ srcsL, float* __restrict__ invdegL){
  __shared__ int cnt[512];
  __shared__ int scan[512];
  int tid = threadIdx.x;
  cnt[tid] = 0;
  __syncthreads();
  for (int e = tid; e < Ee; e += 512) atomicAdd(&cnt[eidx[NE + e]], 1);
  __syncthreads();
  int c = cnt[tid];
  scan[tid] = c;
  __syncthreads();
  for (int off = 1; off < 512; off <<= 1){
    int v = (tid >= off) ? scan[tid-off] : 0;
    __syncthreads();
    scan[tid] += v;
    __syncthreads();
  }
  int excl = scan[tid] - c;
  rowptrL[tid] = excl;
  if (tid == 0) rowptrL[512] = Ee;
  invdegL[tid] = 1.0f / fmaxf((float)c, 1.0f);
  __syncthreads();
  scan[tid] = excl;
  cnt[tid] = 0;
  __syncthreads();
  for (int e = tid; e < Ee; e += 512){
    int d = eidx[NE + e];
    int pos = scan[d] + atomicAdd(&cnt[d], 1);
    srcsL[pos] = eidx[e];
  }
}

// Pack Wbig[128 cols x 4 gates][K=160] into B-frag order.
// flat = (((g*8 + w)*20 + slot)*16 + c)*8 + j ; col = w*16 + c ; k = slot*8 + j
// K: [0,18)=x2=[xn,f0..f15,gcn] (bf16); [18,32)=0; [32,160)=h (fp16!)
__global__ __launch_bounds__(256) void k_wpack(const float* __restrict__ W_ih, const float* __restrict__ W_hh,
                                               unsigned short* __restrict__ Wpack){
  int idx = blockIdx.x*256 + threadIdx.x;
  if (idx >= WPN) return;
  int j = idx & 7;
  int r = idx >> 3;
  int c = r & 15; r >>= 4;
  int slot = r % NSLOT; r /= NSLOT;
  int w = r & 7; int g = r >> 3;
  int k = slot*8 + j;
  int col = w*16 + c;               // 0..127
  float v = 0.f;
  if (g == 0 || g == 1){            // r, z : fused x2 + h
    int row = (g == 0) ? col : 128 + col;
    if (k < 32){ if (k < 18) v = W_ih[row*18 + k]; }
    else v = W_hh[(size_t)row*128 + (k-32)];
  } else if (g == 2){               // i_n : x2 only
    if (k < 18) v = W_ih[(256+col)*18 + k];
  } else {                          // h_n : h only
    if (k >= 32) v = W_hh[(size_t)(256+col)*128 + (k-32)];
  }
  unsigned short enc;
  if (k < 32) enc = f2bfu(v);                         // bf16 slot (x2 part)
  else { __half hh = __float2half(v); enc = *(unsigned short*)&hh; }  // fp16 slot (h part)
  Wpack[idx] = enc;
}

// sfeat = feat·W_nb[1:17]; pre(rootf) = feat·W_root[1:17]; xfb = bf16(feat)
__global__ __launch_bounds__(256) void k_sfeat(const float* __restrict__ feature, const float* __restrict__ W_nb,
                                               const float* __restrict__ W_root,
                                               float* __restrict__ sfeat, float* __restrict__ rootf,
                                               unsigned short* __restrict__ xfb){
  int idx = blockIdx.x*256 + threadIdx.x;
  if (idx >= FW*BN) return;
  int t = idx >> 16, g = idx & 0xFFFF;
  int b = g>>9, n = g&511;
  const float* f = feature + (((size_t)b*THIST + HIST + t)*Nn + n)*Ff;
  unsigned short xv[16];
  float s = 0.f, r = 0.f;
  #pragma unroll
  for (int k = 0; k < Ff; k++){
    float v = f[k];
    s = fmaf(v, W_nb[1+k], s); r = fmaf(v, W_root[1+k], r);
    xv[k] = f2bfu(v);
  }
  sfeat[idx] = s; rootf[idx] = r;
  *(bf16x8*)&xfb[(size_t)idx*16]     = *(bf16x8*)&xv[0];
  *(bf16x8*)&xfb[(size_t)idx*16 + 8] = *(bf16x8*)&xv[8];
}

// pre[t][g] = invdegL[n]*sum sfeat[t][b][src] + pre[t][g] + b_nb
__global__ __launch_bounds__(256) void k_aggT(const int* __restrict__ rowptrL, const int* __restrict__ srcsL,
                                              const float* __restrict__ sfeat, const float* __restrict__ invdegL,
                                              const float* __restrict__ b_nb, float* __restrict__ pre){
  int idx = blockIdx.x*256 + threadIdx.x;
  if (idx >= FW*BN) return;
  int g = idx & 0xFFFF, t = idx >> 16;
  int n = g & 511, b = g >> 9;
  int e0 = rowptrL[n], e1 = rowptrL[n+1];
  const float* sf = sfeat + (size_t)t*BN + (size_t)b*Nn;
  float s = 0.f;
  for (int e = e0; e < e1; e++) s += sf[srcsL[e]];
  pre[idx] = invdegL[n]*s + pre[idx] + b_nb[0];
}

// ---------------- persistent fused recurrence: one block = one batch ----------------
// 512 thr = 8 waves. h state: fp16 in LDS ONLY (master + MFMA A-operand, XOR-swizzled).
// GEMM: kk=0 (x2, bf16 MFMA) + kk=1..4 (h, f16 MFMA), same acc (C/D layout dtype-indep).
// All 20 B-frags preloaded to registers (constant across tiles & steps).
__global__ __launch_bounds__(512, 2) void k_fused(
    const float* __restrict__ pm, const float* __restrict__ pre,
    const float* __restrict__ invdegL, const unsigned short* __restrict__ xfb,
    const int* __restrict__ rowptrL, const int* __restrict__ srcsL,
    const unsigned short* __restrict__ Wpack,
    const float* __restrict__ b_ih, const float* __restrict__ b_hh,
    const float* __restrict__ W_nb, const float* __restrict__ W_root,
    const float* __restrict__ W_out, const float* __restrict__ b_out,
    float* __restrict__ out)
{
  extern __shared__ char smem[];
  short* h_lds  = (short*)smem;                 // [512][128] fp16, chunk16B idx ^= row&15
  short* x2_lds = (short*)(smem + 131072);      // [4][64][8] bf16
  float* xn_lds = (float*)(smem + 135168);      // [2][512]
  float* xnpart = (float*)(smem + 139264);      // [8][64]

  const int tid = threadIdx.x;
  const int b = blockIdx.x;
  const int l = tid & 63, w = tid >> 6;
  const int c = l & 15, lg = l >> 4;

  // init h=0 (fp16 zero bits), xn[0] = last pm25
  {
    bf16x8 z = {};
    for (int i = tid; i < 512*128/8; i += 512) ((bf16x8*)h_lds)[i] = z;
    xn_lds[tid] = pm[((size_t)b*HIST + (HIST-1))*Nn + tid];
  }

  // preload B-fragments: 4 bf16 (x2) + 16 fp16 (h) = 80 VGPR
  bf16x8 bv0[4];
  f16x8  bvh[4][4];
  #pragma unroll
  for (int g = 0; g < 4; g++){
    bv0[g] = *(const bf16x8*)&Wpack[(size_t)(((g*8 + w)*NSLOT + lg)*16 + c)*8];
    #pragma unroll
    for (int kk = 0; kk < 4; kk++)
      bvh[g][kk] = *(const f16x8*)&Wpack[(size_t)(((g*8 + w)*NSLOT + 4 + kk*4 + lg)*16 + c)*8];
  }

  const int j = w*16 + c;
  const float bR = b_ih[j] + b_hh[j];
  const float bZ = b_ih[128+j] + b_hh[128+j];
  const float bI = b_ih[256+j];
  const float bH = b_hh[256+j];
  const float wo = W_out[j];
  const float wnb0 = W_nb[0], wrt0 = W_root[0], bo = b_out[0];
  __syncthreads();

  for (int t = 0; t < FW; t++){
    const float* xn_cur = xn_lds + (t&1)*512;
    float* xn_nxt = xn_lds + ((t&1)^1)*512;
    const float* pre_t = pre + (size_t)t*BN + (size_t)b*Nn;
    const unsigned short* xfb_t = xfb + ((size_t)t*BN + (size_t)b*Nn)*16;

    for (int t8 = 0; t8 < 8; t8++){
      const int tb = t8*64;
      // --- phase A: SX gather (8 thr/node) + gcn + x2 stage ---
      {
        int m = tid >> 3, sub = tid & 7;
        int n = tb + m;
        int e0 = rowptrL[n], e1 = rowptrL[n+1];
        float sx = 0.f;
        for (int e = e0 + sub; e < e1; e += 8) sx += xn_cur[srcsL[e]];
        sx += __shfl_xor(sx, 1); sx += __shfl_xor(sx, 2); sx += __shfl_xor(sx, 4);
        if (sub == 0){
          float xv = xn_cur[n];
          float prea = pre_t[n] + invdegL[n]*wnb0*sx + wrt0*xv;
          float gcn = sigm(prea);
          const bf16x8* xf = (const bf16x8*)&xfb_t[(size_t)n*16];
          bf16x8 x0 = xf[0], x1 = xf[1];
          short v[32];
          v[0] = (short)f2bfu(xv);
          #pragma unroll
          for (int k = 0; k < 8; k++){ v[1+k] = x0[k]; v[9+k] = x1[k]; }
          v[17] = (short)f2bfu(gcn);
          #pragma unroll
          for (int k = 18; k < 32; k++) v[k] = 0;
          #pragma unroll
          for (int s = 0; s < 4; s++)
            *(bf16x8*)&x2_lds[(s*64 + m)*8] = *(bf16x8*)&v[s*8];
        }
      }
      __syncthreads();

      // --- phase B: GEMM [64 x 160] x [160 x 512], mixed bf16/f16 MFMA ---
      f32x4 acc[4][4] = {};   // [gate][m]
      {
        bf16x8 a0[4];
        #pragma unroll
        for (int m = 0; m < 4; m++)
          a0[m] = *(const bf16x8*)&x2_lds[(lg*64 + m*16 + c)*8];
        #pragma unroll
        for (int g = 0; g < 4; g++)
          #pragma unroll
          for (int m = 0; m < 4; m++)
            acc[g][m] = __builtin_amdgcn_mfma_f32_16x16x32_bf16(a0[m], bv0[g], acc[g][m], 0, 0, 0);
      }
      #pragma unroll
      for (int kk = 0; kk < 4; kk++){
        f16x8 a[4];
        int sh = kk*4 + lg;
        #pragma unroll
        for (int m = 0; m < 4; m++){
          int row = tb + m*16 + c;
          a[m] = *(const f16x8*)&h_lds[row*128 + ((sh ^ c)*8)];
        }
        #pragma unroll
        for (int g = 0; g < 4; g++)
          #pragma unroll
          for (int m = 0; m < 4; m++)
            acc[g][m] = __builtin_amdgcn_mfma_f32_16x16x32_f16(a[m], bvh[g][kk], acc[g][m], 0, 0, 0);
      }
      __syncthreads();

      // --- phase C: GRU epilogue (register-local), fp16 h carry in LDS ---
      float psum[4][4];
      #pragma unroll
      for (int m = 0; m < 4; m++){
        #pragma unroll
        for (int q = 0; q < 4; q++){
          int rl = lg*4 + q;
          int row = tb + m*16 + rl;
          int haddr = row*128 + (((j>>3) ^ rl)*8) + (j&7);
          float hold = __half2float(((const __half*)h_lds)[haddr]);
          float rr = sigm(acc[0][m][q] + bR);
          float zz = sigm(acc[1][m][q] + bZ);
          float nn = tanh_f(acc[2][m][q] + bI + rr*(acc[3][m][q] + bH));
          float hv = (1.f - zz)*nn + zz*hold;
          ((__half*)h_lds)[haddr] = __float2half(hv);
          psum[m][q] = hv * wo;
        }
      }
      #pragma unroll
      for (int mask = 1; mask < 16; mask <<= 1){
        #pragma unroll
        for (int m = 0; m < 4; m++)
          #pragma unroll
          for (int q = 0; q < 4; q++)
            psum[m][q] += __shfl_xor(psum[m][q], mask);
      }
      if (c == 0){
        #pragma unroll
        for (int m = 0; m < 4; m++)
          #pragma unroll
          for (int q = 0; q < 4; q++)
            xnpart[w*64 + m*16 + lg*4 + q] = psum[m][q];
      }
      __syncthreads();

      // --- phase D: xn finalize ---
      if (tid < 64){
        int row = tb + tid;
        float xv = bo;
        #pragma unroll
        for (int ww = 0; ww < 8; ww++) xv += xnpart[ww*64 + tid];
        xn_nxt[row] = xv;
        out[((size_t)b*FW + t)*Nn + row] = xv;
      }
    }
    __syncthreads();   // step boundary: xn_nxt complete before next step reads it
  }
}

extern "C" void kernel_launch(void* const* d_in, const int* in_sizes, int n_in,
                              void* d_out, int out_size, void* d_ws, size_t ws_size,
                              hipStream_t stream){
  const float* feature = (const float*)d_in[0];
  const float* pm25    = (const float*)d_in[1];
  const int*   eidx    = (const int*)d_in[2];
  const float* W_nb    = (const float*)d_in[3];
  const float* b_nb    = (const float*)d_in[4];
  const float* W_root  = (const float*)d_in[5];
  const float* W_ih    = (const float*)d_in[6];
  const float* W_hh    = (const float*)d_in[7];
  const float* b_ih    = (const float*)d_in[8];
  const float* b_hh    = (const float*)d_in[9];
  const float* W_out   = (const float*)d_in[10];
  const float* b_out   = (const float*)d_in[11];
  float* out = (float*)d_out;

  char* wsp = (char*)d_ws;
  float* invdegL = (float*)wsp; wsp += 512*4;
  int*   rowptrL = (int*)wsp;   wsp += 520*4;
  int*   srcsL   = (int*)wsp;   wsp += Ee*4;
  float* sfeat   = (float*)wsp; wsp += (size_t)FW*BN*4;
  float* pre     = (float*)wsp; wsp += (size_t)FW*BN*4;
  unsigned short* xfb = (unsigned short*)wsp; wsp += (size_t)FW*BN*16*2;
  unsigned short* Wpack = (unsigned short*)wsp; wsp += (size_t)WPN*2;

  hipFuncSetAttribute((const void*)k_fused, hipFuncAttributeMaxDynamicSharedMemorySize, LDS_BYTES);

  k_csr   <<<1, 512, 0, stream>>>(eidx, rowptrL, srcsL, invdegL);
  k_wpack <<<(WPN+255)/256, 256, 0, stream>>>(W_ih, W_hh, Wpack);
  k_sfeat <<<(FW*BN)/256, 256, 0, stream>>>(feature, W_nb, W_root, sfeat, pre, xfb);
  k_aggT  <<<(FW*BN)/256, 256, 0, stream>>>(rowptrL, srcsL, sfeat, invdegL, b_nb, pre);

  k_fused<<<Bb, 512, LDS_BYTES, stream>>>(pm25, pre, invdegL, xfb, rowptrL, srcsL, Wpack,
                                          b_ih, b_hh, W_nb, W_root, W_out, b_out, out);
}